// Round 5
// baseline (165.261 us; speedup 1.0000x reference)
//
#include <hip/hip_runtime.h>
#include <hip/hip_bf16.h>
#include <math.h>

#define TPB 512
#define XS    132           // f32 X region el-stride (dwords); x -> gp(f32) -> down-out scratch
#define OFF_X  0            // bytes [0,32768) reused as h_bf double buffer in phase D
#define OFF_XR 8448         // [64][17] uint4: xr; later attW [8i][8p][64b^swz] u32
#define XRU4   2112         // OFF_XR/4 : uint4 index of XR region
#define SMEM_FLOATS (8448 + 4352)       // 12800 dwords = 51200 B
#define SMEM_BYTES  (SMEM_FLOATS * 4)

// ---- Cl(3,0): slot s (0..43) of the GP pair-sum (verified round 4 of prior session) ----
constexpr int SCNT[44] = {1,1,1,1,1,1,1,1, 3,1,1,1, 2,2,2,2,2,2, 1,1,1, 3,
                          3, 2,2,2, 1,1,1,1,1,1, 2,2,2, 3, 1,1,1,1,1,1,1,1};
constexpr int T1I[44] = {0,0,0,0,0,0,0,0, 1,1,2,3, 2,1,1,1,1,2, 3,2,1, 1,
                         4, 4,4,5, 6,5,4,4,5,6, 5,4,4, 4, 7,7,7,7,7,7,7,7};
constexpr int T1K[44] = {0,1,2,3,4,5,6,7, 1,0,0,0, 4,4,5,2,3,3, 7,7,7, 6,
                         4, 2,1,1, 7,7,7,0,0,0, 6,6,5, 3, 7,6,5,4,3,2,1,0};
constexpr int T1S[44] = {1,1,1,1,1,1,1,1, 1,1,1,1, 0,1,1,1,1,1, 1,0,1, 1,
                         0, 1,0,0, 0,1,0,1,1,1, 0,1,0, 1, 0,0,1,0,1,0,1,1};
constexpr int T2I[44] = {0,0,0,0,0,0,0,0, 2,0,0,0, 3,3,2,2,3,3, 0,0,0, 2,
                         5, 5,6,6, 0,0,0,0,0,0, 6,6,5, 5, 0,0,0,0,0,0,0,0};
constexpr int T2K[44] = {0,0,0,0,0,0,0,0, 2,0,0,0, 5,6,6,1,1,2, 0,0,0, 5,
                         5, 3,3,2, 0,0,0,0,0,0, 5,4,4, 2, 0,0,0,0,0,0,0,0};
constexpr int T2S[44] = {1,1,1,1,1,1,1,1, 1,1,1,1, 0,0,1,0,0,0, 1,1,1, 0,
                         0, 1,1,0, 1,1,1,1,1,1, 1,0,1, 0, 1,1,1,1,1,1,1,1};
constexpr int T3I[44] = {0,0,0,0,0,0,0,0, 3,0,0,0, 0,0,0,0,0,0, 0,0,0, 3,
                         6, 0,0,0, 0,0,0,0,0,0, 0,0,0, 6, 0,0,0,0,0,0,0,0};
constexpr int T3K[44] = {0,0,0,0,0,0,0,0, 3,0,0,0, 0,0,0,0,0,0, 0,0,0, 4,
                         6, 0,0,0, 0,0,0,0,0,0, 0,0,0, 1, 0,0,0,0,0,0,0,0};
constexpr int T3S[44] = {1,1,1,1,1,1,1,1, 1,1,1,1, 1,1,1,1,1,1, 1,1,1, 1,
                         0, 1,1,1, 1,1,1,1,1,1, 1,1,1, 1, 1,1,1,1,1,1,1,1};
constexpr int CP[44] = {
    0, 1,1,1, 2,2,2, 3,
    4, 5,5,5, 6,6,6, 7,7,7, 8,8,8, 9,
    10, 11,11,11, 12,12,12, 13,13,13, 14,14,14, 15,
    16, 17,17,17, 18,18,18, 19};
// slot-PAIRS for the GP MFMA: k = 2n + slot. Q = jh*11 + p. Both slots of a pair share j.
constexpr int PPS[22][2] = {
    {0,8},{22,36}, {1,9},{12,23},{26,37}, {2,10},{13,24},{27,38}, {3,11},{14,25},{28,39},
    {4,15},{18,29},{32,40}, {5,16},{19,30},{33,41}, {6,17},{20,31},{34,42}, {7,21},{35,43}};
constexpr int FRS[22] = {0,0, 1,1,1, 2,2,2, 3,3,3,  0,0,0, 1,1,1, 2,2,2, 3,3};

typedef __attribute__((ext_vector_type(8))) short bf16x8;
typedef __attribute__((ext_vector_type(4))) float f32x4;
union U4B { uint4 u; bf16x8 h; };

__device__ __forceinline__ float sigmoidf_(float v) {
    return __builtin_amdgcn_rcpf(1.0f + __expf(-v));
}
__device__ __forceinline__ unsigned pk2(float lo, float hi) {
    __hip_bfloat162 h = __float22bfloat162_rn(make_float2(lo, hi));
    return *reinterpret_cast<unsigned*>(&h);
}
__device__ __forceinline__ unsigned bfb(float v) {
    __hip_bfloat16 h = __float2bfloat16(v);
    return (unsigned)*reinterpret_cast<unsigned short*>(&h);
}
__device__ __forceinline__ uint4 pkrow(const float* v) {
    return make_uint4(pk2(v[0],v[1]), pk2(v[2],v[3]), pk2(v[4],v[5]), pk2(v[6],v[7]));
}
__device__ __forceinline__ void unpkrow(uint4 u, float* v) {
    v[0]=__uint_as_float(u.x<<16); v[1]=__uint_as_float(u.x&0xffff0000u);
    v[2]=__uint_as_float(u.y<<16); v[3]=__uint_as_float(u.y&0xffff0000u);
    v[4]=__uint_as_float(u.z<<16); v[5]=__uint_as_float(u.z&0xffff0000u);
    v[6]=__uint_as_float(u.w<<16); v[7]=__uint_as_float(u.w&0xffff0000u);
}
// h_bf swizzled u32 index: writer banks = 8*lh + (np^..), reader banks injective -> both conflict-free
__device__ __forceinline__ int HDW(int i, int row, int np) {
    return (i<<9) | ((row&3)<<7) | (((row>>2)&15)<<3) | (np ^ (row&7));
}

// tz for slot S (compile-time): identical math to the old 44-slot loop
template<int S>
__device__ __forceinline__ float tz_slot(const float* xf, const float* xr) {
    float v = xf[T1I[S]] * xr[T1K[S]];
    if constexpr (!T1S[S]) v = -v;
    if constexpr (SCNT[S] > 1) {
        if constexpr (T2S[S]) v = fmaf( xf[T2I[S]], xr[T2K[S]], v);
        else                  v = fmaf(-xf[T2I[S]], xr[T2K[S]], v);
    }
    if constexpr (SCNT[S] > 2) {
        if constexpr (T3S[S]) v = fmaf( xf[T3I[S]], xr[T3K[S]], v);
        else                  v = fmaf(-xf[T3I[S]], xr[T3K[S]], v);
    }
    return v;
}

template<int JH, int P>
__device__ __forceinline__ void gp_all(const float (&xf)[4][8], const float (&xrf)[4][8],
                                       const uint4* __restrict__ wsg, int lane,
                                       f32x4 (&cf)[4]) {
    if constexpr (P < 11) {
        constexpr int Q  = JH*11 + P;
        constexpr int S0 = PPS[Q][0], S1 = PPS[Q][1], F = FRS[Q];
        U4B a;
        a.u.x = pk2(tz_slot<S0>(xf[0], xrf[0]), tz_slot<S1>(xf[0], xrf[0]));
        a.u.y = pk2(tz_slot<S0>(xf[1], xrf[1]), tz_slot<S1>(xf[1], xrf[1]));
        a.u.z = pk2(tz_slot<S0>(xf[2], xrf[2]), tz_slot<S1>(xf[2], xrf[2]));
        a.u.w = pk2(tz_slot<S0>(xf[3], xrf[3]), tz_slot<S1>(xf[3], xrf[3]));
        U4B wb; wb.u = wsg[Q*64 + lane];
        cf[F] = __builtin_amdgcn_mfma_f32_16x16x32_bf16(a.h, wb.h, cf[F], 0, 0, 0);
        gp_all<JH, P+1>(xf, xrf, wsg, lane, cf);
    }
}

// ---- prep: pack w_up / w_down / w_gp into B-fragment-ordered bf16 pairs ----
// sigma (verified r1): lane l holds col=l&15, k-slots k0 = 8*(l>>4)+2*jp (+1)
// up/down: k = n (>=16 -> 0).  gp: k = 2n+slot -> n = 4*(l>>4)+jp, slots = PPS[Q]
__global__ void prep_pack(const float* __restrict__ w_up,
                          const float* __restrict__ w_down,
                          const float* __restrict__ w_gp,
                          unsigned* __restrict__ wsu,
                          unsigned* __restrict__ wsd,
                          uint4* __restrict__ wsg)
{
    const int t = blockIdx.x * 256 + threadIdx.x;       // 0..17919
    if (t < 16384) {
        const int d  = t & 8191;
        const int f  = d >> 8;                          // 0..31
        const int rj = d & 255;
        const int l  = rj >> 2, jp = rj & 3;
        const int ch = f >> 3, i = f & 7;
        const int g  = (i == 0) ? 0 : (i <= 3 ? 1 : (i <= 6 ? 2 : 3));
        const int k0 = ((l >> 4) << 3) + (jp << 1);
        if (t < 8192) {
            const int m2 = (ch << 4) + (l & 15);
            const float v0 = (k0     < 16) ? w_up[(m2*16 + k0    )*4 + g] : 0.f;
            const float v1 = (k0 + 1 < 16) ? w_up[(m2*16 + k0 + 1)*4 + g] : 0.f;
            wsu[d] = pk2(v0, v1);
        } else {
            const int m = l & 15;
            const float v0 = (k0     < 16) ? w_down[(m*64 + (ch<<4) + k0    )*4 + g] : 0.f;
            const float v1 = (k0 + 1 < 16) ? w_down[(m*64 + (ch<<4) + k0 + 1)*4 + g] : 0.f;
            wsd[d] = pk2(v0, v1);
        }
    } else {
        const int u = t - 16384;                        // 0..1535
        if (u < 1408) {
            const int l = u & 63, q = u >> 6;           // q 0..21
            const int m = l & 15, lh = l >> 4;
            const int s0 = PPS[q][0], s1 = PPS[q][1];
            uint4 val;
            {
                const int n = 4*lh + 0;
                val.x = pk2(w_gp[(m*16+n)*20 + CP[s0]], w_gp[(m*16+n)*20 + CP[s1]]);
            }
            {
                const int n = 4*lh + 1;
                val.y = pk2(w_gp[(m*16+n)*20 + CP[s0]], w_gp[(m*16+n)*20 + CP[s1]]);
            }
            {
                const int n = 4*lh + 2;
                val.z = pk2(w_gp[(m*16+n)*20 + CP[s0]], w_gp[(m*16+n)*20 + CP[s1]]);
            }
            {
                const int n = 4*lh + 3;
                val.w = pk2(w_gp[(m*16+n)*20 + CP[s0]], w_gp[(m*16+n)*20 + CP[s1]]);
            }
            wsg[q*64 + l] = val;
        }
    }
}

__global__ __launch_bounds__(TPB, 4)
void mv_block_kernel(const float* __restrict__ xg,
                     const float* __restrict__ w_right,
                     const float* __restrict__ a_norm,
                     const float* __restrict__ w_gp,
                     const float* __restrict__ w_left,
                     const float* __restrict__ b_left,
                     const float* __restrict__ w_up,
                     const float* __restrict__ b_up,
                     const float* __restrict__ a_act,
                     const float* __restrict__ b_act,
                     const float* __restrict__ w_down,
                     const float* __restrict__ b_down,
                     const uint4* __restrict__ wsu,
                     const uint4* __restrict__ wsd,
                     const uint4* __restrict__ wsg,
                     float* __restrict__ outg)
{
    extern __shared__ float sm[];
    uint4* uXR = ((uint4*)sm) + XRU4;
    const int t = threadIdx.x;
    const int b = t & 63;                                   // lane
    const int w = __builtin_amdgcn_readfirstlane(t >> 6);   // wave 0..7 (uniform)
    const int mA = 2*w, mB = 2*w + 1;                       // adjacent channel pair
    const int g = blockIdx.x;
    // MFMA tile roles (phases C and D)
    const int Mtb  = (w & 3) << 4;                          // M-tile base (16 batch rows)
    const int jh   = w >> 2;                                // blade-half 0/1
    const int lcol = b & 15;
    const int lh   = b >> 4;

    // ---------- stage x (coalesced, f32) ----------
    {
        const float4* xs = (const float4*)xg + (size_t)g * 2048;
        #pragma unroll
        for (int r = 0; r < 4; ++r) {
            const int idx = r * TPB + t;
            const float4 v = xs[idx];
            const int el = idx >> 5, off = idx & 31;
            *(float4*)&sm[OFF_X + el * XS + off * 4] = v;
        }
    }
    __syncthreads();

    // ---------- phase A: right-linear + left-linear (2 channels, weights in SGPRs) ----------
    float xrA[8] = {0,0,0,0,0,0,0,0}, xrB[8] = {0,0,0,0,0,0,0,0};
    float lfA[8] = {0,0,0,0,0,0,0,0}, lfB[8] = {0,0,0,0,0,0,0,0};
    {
        const float* sx = &sm[OFF_X + b * XS];
        #pragma unroll 4
        for (int n = 0; n < 16; ++n) {
            const float4 xa = *(const float4*)&sx[n*8];
            const float4 xb = *(const float4*)&sx[n*8+4];
            const float4 wa = *(const float4*)&w_right[(mA*16+n)*4];
            const float4 wb = *(const float4*)&w_right[(mB*16+n)*4];
            const float4 va = *(const float4*)&w_left [(mA*16+n)*4];
            const float4 vb = *(const float4*)&w_left [(mB*16+n)*4];
            xrA[0]+=xa.x*wa.x; xrA[1]+=xa.y*wa.y; xrA[2]+=xa.z*wa.y; xrA[3]+=xa.w*wa.y;
            xrA[4]+=xb.x*wa.z; xrA[5]+=xb.y*wa.z; xrA[6]+=xb.z*wa.z; xrA[7]+=xb.w*wa.w;
            xrB[0]+=xa.x*wb.x; xrB[1]+=xa.y*wb.y; xrB[2]+=xa.z*wb.y; xrB[3]+=xa.w*wb.y;
            xrB[4]+=xb.x*wb.z; xrB[5]+=xb.y*wb.z; xrB[6]+=xb.z*wb.z; xrB[7]+=xb.w*wb.w;
            lfA[0]+=xa.x*va.x; lfA[1]+=xa.y*va.y; lfA[2]+=xa.z*va.y; lfA[3]+=xa.w*va.y;
            lfA[4]+=xb.x*va.z; lfA[5]+=xb.y*va.z; lfA[6]+=xb.z*va.z; lfA[7]+=xb.w*va.w;
            lfB[0]+=xa.x*vb.x; lfB[1]+=xa.y*vb.y; lfB[2]+=xa.z*vb.y; lfB[3]+=xa.w*vb.y;
            lfB[4]+=xb.x*vb.z; lfB[5]+=xb.y*vb.z; lfB[6]+=xb.z*vb.z; lfB[7]+=xb.w*vb.w;
        }
    }

    // ---------- phase B: gated per-grade normalization ----------
    #pragma unroll
    for (int q = 0; q < 2; ++q) {
        float* xr = q ? xrB : xrA;
        const int m = q ? mB : mA;
        const float q0 = xr[0]*xr[0];
        const float q1 = xr[1]*xr[1] + xr[2]*xr[2] + xr[3]*xr[3];
        const float q2 = xr[4]*xr[4] + xr[5]*xr[5] + xr[6]*xr[6];
        const float q3 = xr[7]*xr[7];
        const float4 an = *(const float4*)&a_norm[m*4];
        const float i0 = __builtin_amdgcn_rcpf(sigmoidf_(an.x)*(sqrtf(q0)-1.0f)+1.0f + 1e-6f);
        const float i1 = __builtin_amdgcn_rcpf(sigmoidf_(an.y)*(sqrtf(q1)-1.0f)+1.0f + 1e-6f);
        const float i2 = __builtin_amdgcn_rcpf(sigmoidf_(an.z)*(sqrtf(q2)-1.0f)+1.0f + 1e-6f);
        const float i3 = __builtin_amdgcn_rcpf(sigmoidf_(an.w)*(sqrtf(q3)-1.0f)+1.0f + 1e-6f);
        xr[0]*=i0; xr[1]*=i1; xr[2]*=i1; xr[3]*=i1;
        xr[4]*=i2; xr[5]*=i2; xr[6]*=i2; xr[7]*=i3;
    }
    uXR[b*17 + mA] = pkrow(xrA);     // xr -> bf16 LDS (1 uint4 per channel)
    uXR[b*17 + mB] = pkrow(xrB);
    __syncthreads();

    // ---------- phase C (MFMA GP): products -> A-frags in registers -> 11 MFMAs ----------
    {
        const int brow = Mtb + lcol;
        float xf[4][8], xrf[4][8];
        #pragma unroll
        for (int jp = 0; jp < 4; ++jp) {
            const int n = 4*lh + jp;
            const float4 u0 = *(const float4*)&sm[OFF_X + brow*XS + n*8];
            const float4 u1 = *(const float4*)&sm[OFF_X + brow*XS + n*8 + 4];
            xf[jp][0]=u0.x; xf[jp][1]=u0.y; xf[jp][2]=u0.z; xf[jp][3]=u0.w;
            xf[jp][4]=u1.x; xf[jp][5]=u1.y; xf[jp][6]=u1.z; xf[jp][7]=u1.w;
            unpkrow(uXR[brow*17 + n], xrf[jp]);
        }
        f32x4 cf[4];
        #pragma unroll
        for (int q = 0; q < 4; ++q) { cf[q][0]=0.f; cf[q][1]=0.f; cf[q][2]=0.f; cf[q][3]=0.f; }
        if (jh == 0) gp_all<0,0>(xf, xrf, wsg, b, cf);
        else         gp_all<1,0>(xf, xrf, wsg, b, cf);
        __syncthreads();   // all waves done reading x (X) and xr (uXR)
        // gp -> X region f32 [b][m*8 + j]  (x is dead)
        #pragma unroll
        for (int r = 0; r < 4; ++r) {
            *(float4*)&sm[OFF_X + (Mtb + 4*lh + r)*XS + (lcol<<3) + (jh<<2)] =
                make_float4(cf[0][r], cf[1][r], cf[2][r], cf[3][r]);
        }
    }
    __syncthreads();

    // ---------- attended = (left + b_left + gp)/sqrt(2); regs only ----------
    float gpA[8], gpB[8];
    {
        const float* gx = &sm[OFF_X + b*XS];
        const float4 g0 = *(const float4*)&gx[mA*8];
        const float4 g1 = *(const float4*)&gx[mA*8 + 4];
        gpA[0]=g0.x; gpA[1]=g0.y; gpA[2]=g0.z; gpA[3]=g0.w;
        gpA[4]=g1.x; gpA[5]=g1.y; gpA[6]=g1.z; gpA[7]=g1.w;
        const float4 h0 = *(const float4*)&gx[mB*8];
        const float4 h1 = *(const float4*)&gx[mB*8 + 4];
        gpB[0]=h0.x; gpB[1]=h0.y; gpB[2]=h0.z; gpB[3]=h0.w;
        gpB[4]=h1.x; gpB[5]=h1.y; gpB[6]=h1.z; gpB[7]=h1.w;
    }
    float attA[8], attB_[8];
    lfA[0] += b_left[mA];
    lfB[0] += b_left[mB];
    #pragma unroll
    for (int i = 0; i < 8; ++i) {
        attA[i]  = (lfA[i] + gpA[i]) * 0.70710678118654752f;
        attB_[i] = (lfB[i] + gpB[i]) * 0.70710678118654752f;
    }
    // direct reg -> att_bf [i][p=w][b ^ ((p>>2)<<4)] u32; writer 2-way free, reader conflict-free
    {
        unsigned* attW = (unsigned*)(sm + OFF_XR);
        const int bsw = b ^ ((w >> 2) << 4);
        #pragma unroll
        for (int i = 0; i < 8; ++i)
            attW[(i<<9) + (w<<6) + bsw] = pk2(attA[i], attB_[i]);
    }
    __syncthreads();

    // ---------- phase D (MFMA): per-blade up-GEMM -> in-register silu -> per-blade down-GEMM ----------
    unsigned* hW = (unsigned*)sm;                 // X bytes [0,32768): h_bf double buffer (u32 units)
    f32x4 dC[4];
    #pragma unroll
    for (int q = 0; q < 4; ++q) { dC[q][0]=0.f; dC[q][1]=0.f; dC[q][2]=0.f; dC[q][3]=0.f; }

    #pragma unroll 1
    for (int ch = 0; ch < 4; ++ch) {
        const int m2 = (ch << 4) + lcol;
        unsigned* hb = hW + ((ch & 1) << 12);     // 4096 u32 = 16KB per buffer
        // --- up: 4 blades, K=16 (upper K zero); swizzled attW reads (conflict-free) ---
        f32x4 uC[4];
        #pragma unroll
        for (int q = 0; q < 4; ++q) {
            const int i = jh*4 + q;
            U4B a; a.u = make_uint4(0u,0u,0u,0u);
            if (lh < 2) {   // k-slots >=16 multiply zero B rows; skip their loads
                const unsigned* aw = (const unsigned*)(sm + OFF_XR) + (i<<9)
                                   + ((Mtb + lcol) ^ (lh << 4));
                a.u.x = aw[(4*lh+0)<<6];
                a.u.y = aw[(4*lh+1)<<6];
                a.u.z = aw[(4*lh+2)<<6];
                a.u.w = aw[(4*lh+3)<<6];
            }
            U4B wb; wb.u = wsu[((ch<<3) + i)*64 + b];
            f32x4 z; z[0]=0.f; z[1]=0.f; z[2]=0.f; z[3]=0.f;
            uC[q] = __builtin_amdgcn_mfma_f32_16x16x32_bf16(a.h, wb.h, z, 0, 0, 0);
        }
        // --- silu in C-layout (grades never cross the blade-quad boundary) ---
        const float4 aact = *(const float4*)&a_act[m2*4];
        const float4 bact = *(const float4*)&b_act[m2*4];
        const float bup = b_up[m2];
        #pragma unroll
        for (int r = 0; r < 4; ++r) {
            float h0 = uC[0][r], h1 = uC[1][r], h2 = uC[2][r], h3 = uC[3][r];
            if (jh == 0) {                       // blades 0..3: grade0 (scalar) + grade1
                h0 += bup;
                const float g0 = sigmoidf_(fmaf(aact.x, h0, bact.x));
                const float g1 = sigmoidf_(fmaf(aact.y, h1*h1 + h2*h2 + h3*h3, bact.y));
                h0 *= g0; h1 *= g1; h2 *= g1; h3 *= g1;
            } else {                             // blades 4..7: grade2 + grade3
                const float g2 = sigmoidf_(fmaf(aact.z, h0*h0 + h1*h1 + h2*h2, bact.z));
                const float g3 = sigmoidf_(fmaf(aact.w, h3*h3, bact.w));
                h0 *= g2; h1 *= g2; h2 *= g2; h3 *= g3;
            }
            uC[0][r]=h0; uC[1][r]=h1; uC[2][r]=h2; uC[3][r]=h3;
        }
        // --- write h_bf: pack (lcol even, odd) u16s via shfl_xor(1) -> even lanes store u32 ---
        // layout HDW: writer banks 8*lh + (np^..) -> conflict-free; double buffer -> no pre-barrier
        #pragma unroll
        for (int q = 0; q < 4; ++q) {
            const int i = jh*4 + q;
            #pragma unroll
            for (int r = 0; r < 4; ++r) {
                const int row = Mtb + (lh<<2) + r;
                const unsigned my = bfb(uC[q][r]);
                const unsigned other = (unsigned)__shfl_xor((int)my, 1, 64);
                if ((lcol & 1) == 0)
                    hb[HDW(i, row, lcol >> 1)] = my | (other << 16);
            }
        }
        __syncthreads();     // h_bf (buffer ch&1) visible
        // --- down: 4 blades, K = this chunk's 16 m2 (upper K zero), accumulate ---
        #pragma unroll
        for (int q = 0; q < 4; ++q) {
            const int i = jh*4 + q;
            U4B a; a.u = make_uint4(0u,0u,0u,0u);
            if (lh < 2) {
                const int row = Mtb + lcol;
                a.u.x = hb[HDW(i, row, 4*lh+0)];
                a.u.y = hb[HDW(i, row, 4*lh+1)];
                a.u.z = hb[HDW(i, row, 4*lh+2)];
                a.u.w = hb[HDW(i, row, 4*lh+3)];
            }
            U4B wb; wb.u = wsd[((ch<<3) + i)*64 + b];
            dC[q] = __builtin_amdgcn_mfma_f32_16x16x32_bf16(a.h, wb.h, dC[q], 0, 0, 0);
        }
    }
    __syncthreads();         // last down-reads done everywhere; X region reusable
    // --- down result -> X f32 in [b][m*8+i] layout ---
    #pragma unroll
    for (int r = 0; r < 4; ++r) {
        const int br = Mtb + (lh<<2) + r;
        *(float4*)&sm[OFF_X + br*XS + (lcol<<3) + (jh<<2)] =
            make_float4(dC[0][r], dC[1][r], dC[2][r], dC[3][r]);
    }
    __syncthreads();

    // ---------- epilogue: out = attended + down + b_down ----------
    {
        const float bdA = b_down[mA], bdB = b_down[mB];
        float4 a0 = *(const float4*)&sm[OFF_X + b*XS + mA*8];
        float4 a1 = *(const float4*)&sm[OFF_X + b*XS + mA*8 + 4];
        float4 b0 = *(const float4*)&sm[OFF_X + b*XS + mB*8];
        float4 b1 = *(const float4*)&sm[OFF_X + b*XS + mB*8 + 4];
        *(float4*)&sm[OFF_X + b*XS + mA*8]     = make_float4(attA[0]+a0.x+bdA, attA[1]+a0.y,
                                                             attA[2]+a0.z,     attA[3]+a0.w);
        *(float4*)&sm[OFF_X + b*XS + mA*8 + 4] = make_float4(attA[4]+a1.x, attA[5]+a1.y,
                                                             attA[6]+a1.z, attA[7]+a1.w);
        *(float4*)&sm[OFF_X + b*XS + mB*8]     = make_float4(attB_[0]+b0.x+bdB, attB_[1]+b0.y,
                                                             attB_[2]+b0.z,     attB_[3]+b0.w);
        *(float4*)&sm[OFF_X + b*XS + mB*8 + 4] = make_float4(attB_[4]+b1.x, attB_[5]+b1.y,
                                                             attB_[6]+b1.z, attB_[7]+b1.w);
    }
    __syncthreads();
    {
        float4* og = (float4*)outg + (size_t)g * 2048;
        #pragma unroll
        for (int r = 0; r < 4; ++r) {
            const int idx = r * TPB + t;
            const int el = idx >> 5, off = idx & 31;
            og[idx] = *(const float4*)&sm[OFF_X + el * XS + off * 4];
        }
    }
}

extern "C" void kernel_launch(void* const* d_in, const int* in_sizes, int n_in,
                              void* d_out, int out_size, void* d_ws, size_t ws_size,
                              hipStream_t stream) {
    const float* x       = (const float*)d_in[0];
    const float* w_right = (const float*)d_in[1];
    const float* a_norm  = (const float*)d_in[2];
    const float* w_gp    = (const float*)d_in[3];
    const float* w_left  = (const float*)d_in[4];
    const float* b_left  = (const float*)d_in[5];
    const float* w_up    = (const float*)d_in[6];
    const float* b_up    = (const float*)d_in[7];
    const float* a_act   = (const float*)d_in[8];
    const float* b_act   = (const float*)d_in[9];
    const float* w_down  = (const float*)d_in[10];
    const float* b_down  = (const float*)d_in[11];
    float* out = (float*)d_out;

    const int B = in_sizes[0] / 128;        // 65536
    const int nblocks = B / 64;             // 1024

    unsigned* wsu = (unsigned*)d_ws;        // 32 KB up B-frags
    unsigned* wsd = wsu + 8192;             // 32 KB down B-frags
    uint4*    wsg = (uint4*)(wsd + 8192);   // 22.5 KB gp B-frags (22 slot-pairs x 64 lanes)

    prep_pack<<<70, 256, 0, stream>>>(w_up, w_down, w_gp, wsu, wsd, wsg);

    (void)hipFuncSetAttribute((const void*)mv_block_kernel,
                              hipFuncAttributeMaxDynamicSharedMemorySize, SMEM_BYTES);
    mv_block_kernel<<<nblocks, TPB, SMEM_BYTES, stream>>>(
        x, w_right, a_norm, w_gp, w_left, b_left,
        w_up, b_up, a_act, b_act, w_down, b_down,
        (const uint4*)wsu, (const uint4*)wsd, (const uint4*)wsg, out);
}

// Round 6
// 151.926 us; speedup vs baseline: 1.0878x; 1.0878x over previous
//
#include <hip/hip_runtime.h>
#include <hip/hip_bf16.h>
#include <math.h>

#define TPB 512
#define XS    132           // f32 X region el-stride (dwords); x -> gp(f32) -> down-out scratch
#define OFF_X  0
#define OFF_XR 8448         // [64][17] uint4: xr; later attW [8i][8np][64b^swz] u32
#define XRU4   2112         // OFF_XR/4 : uint4 index of XR region
#define SMEM_FLOATS (8448 + 4352)       // 12800 dwords = 51200 B
#define SMEM_BYTES  (SMEM_FLOATS * 4)

// ---- Cl(3,0): slot s (0..43) of the GP pair-sum (verified) ----
constexpr int SCNT[44] = {1,1,1,1,1,1,1,1, 3,1,1,1, 2,2,2,2,2,2, 1,1,1, 3,
                          3, 2,2,2, 1,1,1,1,1,1, 2,2,2, 3, 1,1,1,1,1,1,1,1};
constexpr int T1I[44] = {0,0,0,0,0,0,0,0, 1,1,2,3, 2,1,1,1,1,2, 3,2,1, 1,
                         4, 4,4,5, 6,5,4,4,5,6, 5,4,4, 4, 7,7,7,7,7,7,7,7};
constexpr int T1K[44] = {0,1,2,3,4,5,6,7, 1,0,0,0, 4,4,5,2,3,3, 7,7,7, 6,
                         4, 2,1,1, 7,7,7,0,0,0, 6,6,5, 3, 7,6,5,4,3,2,1,0};
constexpr int T1S[44] = {1,1,1,1,1,1,1,1, 1,1,1,1, 0,1,1,1,1,1, 1,0,1, 1,
                         0, 1,0,0, 0,1,0,1,1,1, 0,1,0, 1, 0,0,1,0,1,0,1,1};
constexpr int T2I[44] = {0,0,0,0,0,0,0,0, 2,0,0,0, 3,3,2,2,3,3, 0,0,0, 2,
                         5, 5,6,6, 0,0,0,0,0,0, 6,6,5, 5, 0,0,0,0,0,0,0,0};
constexpr int T2K[44] = {0,0,0,0,0,0,0,0, 2,0,0,0, 5,6,6,1,1,2, 0,0,0, 5,
                         5, 3,3,2, 0,0,0,0,0,0, 5,4,4, 2, 0,0,0,0,0,0,0,0};
constexpr int T2S[44] = {1,1,1,1,1,1,1,1, 1,1,1,1, 0,0,1,0,0,0, 1,1,1, 0,
                         0, 1,1,0, 1,1,1,1,1,1, 1,0,1, 0, 1,1,1,1,1,1,1,1};
constexpr int T3I[44] = {0,0,0,0,0,0,0,0, 3,0,0,0, 0,0,0,0,0,0, 0,0,0, 3,
                         6, 0,0,0, 0,0,0,0,0,0, 0,0,0, 6, 0,0,0,0,0,0,0,0};
constexpr int T3K[44] = {0,0,0,0,0,0,0,0, 3,0,0,0, 0,0,0,0,0,0, 0,0,0, 4,
                         6, 0,0,0, 0,0,0,0,0,0, 0,0,0, 1, 0,0,0,0,0,0,0,0};
constexpr int T3S[44] = {1,1,1,1,1,1,1,1, 1,1,1,1, 1,1,1,1,1,1, 1,1,1, 1,
                         0, 1,1,1, 1,1,1,1,1,1, 1,1,1, 1, 1,1,1,1,1,1,1,1};
constexpr int CP[44] = {
    0, 1,1,1, 2,2,2, 3,
    4, 5,5,5, 6,6,6, 7,7,7, 8,8,8, 9,
    10, 11,11,11, 12,12,12, 13,13,13, 14,14,14, 15,
    16, 17,17,17, 18,18,18, 19};
// slot-PAIRS for the GP MFMA: k = 2n + slot. Q = jh*11 + p. Both slots of a pair share j.
constexpr int PPS[22][2] = {
    {0,8},{22,36}, {1,9},{12,23},{26,37}, {2,10},{13,24},{27,38}, {3,11},{14,25},{28,39},
    {4,15},{18,29},{32,40}, {5,16},{19,30},{33,41}, {6,17},{20,31},{34,42}, {7,21},{35,43}};
constexpr int FRS[22] = {0,0, 1,1,1, 2,2,2, 3,3,3,  0,0,0, 1,1,1, 2,2,2, 3,3};

typedef __attribute__((ext_vector_type(8))) short bf16x8;
typedef __attribute__((ext_vector_type(4))) float f32x4;
union U4B { uint4 u; bf16x8 h; };

__device__ __forceinline__ float sigmoidf_(float v) {
    return __builtin_amdgcn_rcpf(1.0f + __expf(-v));
}
__device__ __forceinline__ unsigned pk2(float lo, float hi) {
    __hip_bfloat162 h = __float22bfloat162_rn(make_float2(lo, hi));
    return *reinterpret_cast<unsigned*>(&h);
}
__device__ __forceinline__ uint4 pkrow(const float* v) {
    return make_uint4(pk2(v[0],v[1]), pk2(v[2],v[3]), pk2(v[4],v[5]), pk2(v[6],v[7]));
}
__device__ __forceinline__ void unpkrow(uint4 u, float* v) {
    v[0]=__uint_as_float(u.x<<16); v[1]=__uint_as_float(u.x&0xffff0000u);
    v[2]=__uint_as_float(u.y<<16); v[3]=__uint_as_float(u.y&0xffff0000u);
    v[4]=__uint_as_float(u.z<<16); v[5]=__uint_as_float(u.z&0xffff0000u);
    v[6]=__uint_as_float(u.w<<16); v[7]=__uint_as_float(u.w&0xffff0000u);
}

// tz for slot S (compile-time): identical math to the reference contraction
template<int S>
__device__ __forceinline__ float tz_slot(const float* xf, const float* xr) {
    float v = xf[T1I[S]] * xr[T1K[S]];
    if constexpr (!T1S[S]) v = -v;
    if constexpr (SCNT[S] > 1) {
        if constexpr (T2S[S]) v = fmaf( xf[T2I[S]], xr[T2K[S]], v);
        else                  v = fmaf(-xf[T2I[S]], xr[T2K[S]], v);
    }
    if constexpr (SCNT[S] > 2) {
        if constexpr (T3S[S]) v = fmaf( xf[T3I[S]], xr[T3K[S]], v);
        else                  v = fmaf(-xf[T3I[S]], xr[T3K[S]], v);
    }
    return v;
}

template<int JH, int P>
__device__ __forceinline__ void gp_all(const float (&xf)[4][8], const float (&xrf)[4][8],
                                       const uint4* __restrict__ wsg, int lane,
                                       f32x4 (&cf)[4]) {
    if constexpr (P < 11) {
        constexpr int Q  = JH*11 + P;
        constexpr int S0 = PPS[Q][0], S1 = PPS[Q][1], F = FRS[Q];
        U4B a;
        a.u.x = pk2(tz_slot<S0>(xf[0], xrf[0]), tz_slot<S1>(xf[0], xrf[0]));
        a.u.y = pk2(tz_slot<S0>(xf[1], xrf[1]), tz_slot<S1>(xf[1], xrf[1]));
        a.u.z = pk2(tz_slot<S0>(xf[2], xrf[2]), tz_slot<S1>(xf[2], xrf[2]));
        a.u.w = pk2(tz_slot<S0>(xf[3], xrf[3]), tz_slot<S1>(xf[3], xrf[3]));
        U4B wb; wb.u = wsg[Q*64 + lane];
        cf[F] = __builtin_amdgcn_mfma_f32_16x16x32_bf16(a.h, wb.h, cf[F], 0, 0, 0);
        gp_all<JH, P+1>(xf, xrf, wsg, lane, cf);
    }
}

// ---- prep: pack w_up (A-frags under pi), w_down (K=32 B-frags), w_gp (B-frags) ----
// sigma (verified): lane l -> row/col = l&15, k-slots ks0 = 8*(l>>4)+2*jp (+1)
// pi(mt,lh,r) = 32*(mt>>1) + 4*(mt&1) + 8*lh + r   (m2 relabeling; see kernel phase D)
__global__ void prep_pack(const float* __restrict__ w_up,
                          const float* __restrict__ w_down,
                          const float* __restrict__ w_gp,
                          unsigned* __restrict__ wsu,
                          unsigned* __restrict__ wsd,
                          uint4* __restrict__ wsg)
{
    const int t = blockIdx.x * 256 + threadIdx.x;       // 0..13823
    if (t < 8192) {
        // wsu: up A-frags. frag f = mt*8 + i. lane row rho = l&15 -> m2 = pi(mt, rho>>2, rho&3)
        const int d  = t;
        const int f  = d >> 8;
        const int rj = d & 255;
        const int l  = rj >> 2, jp = rj & 3;
        const int mt = f >> 3, i = f & 7;
        const int g  = (i == 0) ? 0 : (i <= 3 ? 1 : (i <= 6 ? 2 : 3));
        const int rho = l & 15;
        const int m2 = 32*(mt>>1) + 4*(mt&1) + 8*(rho>>2) + (rho&3);
        const int n0 = ((l >> 4) << 3) + (jp << 1);
        const float v0 = (n0     < 16) ? w_up[(m2*16 + n0    )*4 + g] : 0.f;
        const float v1 = (n0 + 1 < 16) ? w_up[(m2*16 + n0 + 1)*4 + g] : 0.f;
        wsu[d] = pk2(v0, v1);
    } else if (t < 12288) {
        // wsd: down B-frags, K=32. frag f = kt*8 + i. col m = l&15, k = m2 = 32kt + ks (natural under pi)
        const int d  = t - 8192;
        const int f  = d >> 8;
        const int rj = d & 255;
        const int l  = rj >> 2, jp = rj & 3;
        const int kt = f >> 3, i = f & 7;
        const int g  = (i == 0) ? 0 : (i <= 3 ? 1 : (i <= 6 ? 2 : 3));
        const int m  = l & 15;
        const int k0 = 32*kt + ((l >> 4) << 3) + (jp << 1);
        wsd[d] = pk2(w_down[(m*64 + k0    )*4 + g],
                     w_down[(m*64 + k0 + 1)*4 + g]);
    } else {
        const int u = t - 12288;                        // 0..1535
        if (u < 1408) {
            const int l = u & 63, q = u >> 6;           // q 0..21
            const int m = l & 15, lh = l >> 4;
            const int s0 = PPS[q][0], s1 = PPS[q][1];
            uint4 val;
            { const int n = 4*lh + 0;
              val.x = pk2(w_gp[(m*16+n)*20 + CP[s0]], w_gp[(m*16+n)*20 + CP[s1]]); }
            { const int n = 4*lh + 1;
              val.y = pk2(w_gp[(m*16+n)*20 + CP[s0]], w_gp[(m*16+n)*20 + CP[s1]]); }
            { const int n = 4*lh + 2;
              val.z = pk2(w_gp[(m*16+n)*20 + CP[s0]], w_gp[(m*16+n)*20 + CP[s1]]); }
            { const int n = 4*lh + 3;
              val.w = pk2(w_gp[(m*16+n)*20 + CP[s0]], w_gp[(m*16+n)*20 + CP[s1]]); }
            wsg[q*64 + l] = val;
        }
    }
}

__global__ __launch_bounds__(TPB, 4)
void mv_block_kernel(const float* __restrict__ xg,
                     const float* __restrict__ w_right,
                     const float* __restrict__ a_norm,
                     const float* __restrict__ w_gp,
                     const float* __restrict__ w_left,
                     const float* __restrict__ b_left,
                     const float* __restrict__ w_up,
                     const float* __restrict__ b_up,
                     const float* __restrict__ a_act,
                     const float* __restrict__ b_act,
                     const float* __restrict__ w_down,
                     const float* __restrict__ b_down,
                     const uint4* __restrict__ wsu,
                     const uint4* __restrict__ wsd,
                     const uint4* __restrict__ wsg,
                     float* __restrict__ outg)
{
    extern __shared__ float sm[];
    uint4* uXR = ((uint4*)sm) + XRU4;
    const int t = threadIdx.x;
    const int b = t & 63;                                   // lane
    const int w = __builtin_amdgcn_readfirstlane(t >> 6);   // wave 0..7 (uniform)
    const int mA = 2*w, mB = 2*w + 1;                       // adjacent channel pair
    const int g = blockIdx.x;
    const int Mtb  = (w & 3) << 4;                          // M-tile base (16 batch rows)
    const int jh   = w >> 2;                                // blade-half 0/1
    const int lcol = b & 15;
    const int lh   = b >> 4;

    // ---------- stage x (coalesced, f32) ----------
    {
        const float4* xs = (const float4*)xg + (size_t)g * 2048;
        #pragma unroll
        for (int r = 0; r < 4; ++r) {
            const int idx = r * TPB + t;
            const float4 v = xs[idx];
            const int el = idx >> 5, off = idx & 31;
            *(float4*)&sm[OFF_X + el * XS + off * 4] = v;
        }
    }
    __syncthreads();

    // ---------- phase A: right-linear + left-linear (2 channels, weights in SGPRs) ----------
    float xrA[8] = {0,0,0,0,0,0,0,0}, xrB[8] = {0,0,0,0,0,0,0,0};
    float lfA[8] = {0,0,0,0,0,0,0,0}, lfB[8] = {0,0,0,0,0,0,0,0};
    {
        const float* sx = &sm[OFF_X + b * XS];
        #pragma unroll 4
        for (int n = 0; n < 16; ++n) {
            const float4 xa = *(const float4*)&sx[n*8];
            const float4 xb = *(const float4*)&sx[n*8+4];
            const float4 wa = *(const float4*)&w_right[(mA*16+n)*4];
            const float4 wb = *(const float4*)&w_right[(mB*16+n)*4];
            const float4 va = *(const float4*)&w_left [(mA*16+n)*4];
            const float4 vb = *(const float4*)&w_left [(mB*16+n)*4];
            xrA[0]+=xa.x*wa.x; xrA[1]+=xa.y*wa.y; xrA[2]+=xa.z*wa.y; xrA[3]+=xa.w*wa.y;
            xrA[4]+=xb.x*wa.z; xrA[5]+=xb.y*wa.z; xrA[6]+=xb.z*wa.z; xrA[7]+=xb.w*wa.w;
            xrB[0]+=xa.x*wb.x; xrB[1]+=xa.y*wb.y; xrB[2]+=xa.z*wb.y; xrB[3]+=xa.w*wb.y;
            xrB[4]+=xb.x*wb.z; xrB[5]+=xb.y*wb.z; xrB[6]+=xb.z*wb.z; xrB[7]+=xb.w*wb.w;
            lfA[0]+=xa.x*va.x; lfA[1]+=xa.y*va.y; lfA[2]+=xa.z*va.y; lfA[3]+=xa.w*va.y;
            lfA[4]+=xb.x*va.z; lfA[5]+=xb.y*va.z; lfA[6]+=xb.z*va.z; lfA[7]+=xb.w*va.w;
            lfB[0]+=xa.x*vb.x; lfB[1]+=xa.y*vb.y; lfB[2]+=xa.z*vb.y; lfB[3]+=xa.w*vb.y;
            lfB[4]+=xb.x*vb.z; lfB[5]+=xb.y*vb.z; lfB[6]+=xb.z*vb.z; lfB[7]+=xb.w*vb.w;
        }
    }

    // ---------- phase B: gated per-grade normalization ----------
    #pragma unroll
    for (int q = 0; q < 2; ++q) {
        float* xr = q ? xrB : xrA;
        const int m = q ? mB : mA;
        const float q0 = xr[0]*xr[0];
        const float q1 = xr[1]*xr[1] + xr[2]*xr[2] + xr[3]*xr[3];
        const float q2 = xr[4]*xr[4] + xr[5]*xr[5] + xr[6]*xr[6];
        const float q3 = xr[7]*xr[7];
        const float4 an = *(const float4*)&a_norm[m*4];
        const float i0 = __builtin_amdgcn_rcpf(sigmoidf_(an.x)*(sqrtf(q0)-1.0f)+1.0f + 1e-6f);
        const float i1 = __builtin_amdgcn_rcpf(sigmoidf_(an.y)*(sqrtf(q1)-1.0f)+1.0f + 1e-6f);
        const float i2 = __builtin_amdgcn_rcpf(sigmoidf_(an.z)*(sqrtf(q2)-1.0f)+1.0f + 1e-6f);
        const float i3 = __builtin_amdgcn_rcpf(sigmoidf_(an.w)*(sqrtf(q3)-1.0f)+1.0f + 1e-6f);
        xr[0]*=i0; xr[1]*=i1; xr[2]*=i1; xr[3]*=i1;
        xr[4]*=i2; xr[5]*=i2; xr[6]*=i2; xr[7]*=i3;
    }
    uXR[b*17 + mA] = pkrow(xrA);     // xr -> bf16 LDS (1 uint4 per channel)
    uXR[b*17 + mB] = pkrow(xrB);
    __syncthreads();

    // ---------- phase C (MFMA GP): products -> A-frags in registers -> 11 MFMAs ----------
    {
        const int brow = Mtb + lcol;
        float xf[4][8], xrf[4][8];
        #pragma unroll
        for (int jp = 0; jp < 4; ++jp) {
            const int n = 4*lh + jp;
            const float4 u0 = *(const float4*)&sm[OFF_X + brow*XS + n*8];
            const float4 u1 = *(const float4*)&sm[OFF_X + brow*XS + n*8 + 4];
            xf[jp][0]=u0.x; xf[jp][1]=u0.y; xf[jp][2]=u0.z; xf[jp][3]=u0.w;
            xf[jp][4]=u1.x; xf[jp][5]=u1.y; xf[jp][6]=u1.z; xf[jp][7]=u1.w;
            unpkrow(uXR[brow*17 + n], xrf[jp]);
        }
        f32x4 cf[4];
        #pragma unroll
        for (int q = 0; q < 4; ++q) { cf[q][0]=0.f; cf[q][1]=0.f; cf[q][2]=0.f; cf[q][3]=0.f; }
        if (jh == 0) gp_all<0,0>(xf, xrf, wsg, b, cf);
        else         gp_all<1,0>(xf, xrf, wsg, b, cf);
        __syncthreads();   // all waves done reading x (X) and xr (uXR)
        // gp -> X region f32 [b][m*8 + j]  (x is dead)
        #pragma unroll
        for (int r = 0; r < 4; ++r) {
            *(float4*)&sm[OFF_X + (Mtb + 4*lh + r)*XS + (lcol<<3) + (jh<<2)] =
                make_float4(cf[0][r], cf[1][r], cf[2][r], cf[3][r]);
        }
    }
    __syncthreads();

    // ---------- attended = (left + b_left + gp)/sqrt(2); regs only ----------
    float gpA[8], gpB[8];
    {
        const float* gx = &sm[OFF_X + b*XS];
        const float4 g0 = *(const float4*)&gx[mA*8];
        const float4 g1 = *(const float4*)&gx[mA*8 + 4];
        gpA[0]=g0.x; gpA[1]=g0.y; gpA[2]=g0.z; gpA[3]=g0.w;
        gpA[4]=g1.x; gpA[5]=g1.y; gpA[6]=g1.z; gpA[7]=g1.w;
        const float4 h0 = *(const float4*)&gx[mB*8];
        const float4 h1 = *(const float4*)&gx[mB*8 + 4];
        gpB[0]=h0.x; gpB[1]=h0.y; gpB[2]=h0.z; gpB[3]=h0.w;
        gpB[4]=h1.x; gpB[5]=h1.y; gpB[6]=h1.z; gpB[7]=h1.w;
    }
    float attA[8], attB_[8];
    lfA[0] += b_left[mA];
    lfB[0] += b_left[mB];
    #pragma unroll
    for (int i = 0; i < 8; ++i) {
        attA[i]  = (lfA[i] + gpA[i]) * 0.70710678118654752f;
        attB_[i] = (lfB[i] + gpB[i]) * 0.70710678118654752f;
    }
    // att_bf [i][np=w][b ^ ((np>>2)<<4)] u32 (bf16 pair = channels 2w,2w+1)
    // writer: lanes consecutive (conflict-free). reader (phase D B-frags): conflict-free.
    {
        unsigned* attW = (unsigned*)(sm + OFF_XR);
        const int bsw = b ^ ((w >> 2) << 4);
        #pragma unroll
        for (int i = 0; i < 8; ++i)
            attW[(i<<9) + (w<<6) + bsw] = pk2(attA[i], attB_[i]);
    }
    __syncthreads();

    // ---------- phase D: swapped up-GEMM (h^T in regs) -> in-reg silu -> reg-packed down-GEMM ----
    // up (per blade i): C'[m2,b] = wsu(A)[m2,n] x attB(B)[n,b]; C' lane: col=b-local, row=m2-local
    // pi relabel: m2 = 32*(mt>>1) + 4*(mt&1) + 8*lh + r  =>  C' rows align with down A k-slots:
    // down A dword jp of ktile kt = pk2(uc[q][jp>>1][(2jp)&3], uc[q][jp>>1][((2jp)&3)+1]) same lane.
    // down (per blade): dC[b,m] += A(h) x wsd(B), K=32, 2 ktiles. No LDS, no barriers for h.
    f32x4 dC[4];
    #pragma unroll
    for (int q = 0; q < 4; ++q) { dC[q][0]=0.f; dC[q][1]=0.f; dC[q][2]=0.f; dC[q][3]=0.f; }
    {
        // B-frags (att) per blade, loaded once; k>=16 rows multiply zero A -> zeros fine
        uint4 attB[4];
        {
            const unsigned* aw = (const unsigned*)(sm + OFF_XR);
            #pragma unroll
            for (int q = 0; q < 4; ++q) {
                uint4 v = make_uint4(0u,0u,0u,0u);
                if (lh < 2) {
                    const int base = ((jh*4 + q) << 9);
                    const int bb = (Mtb + lcol) ^ (lh << 4);
                    v.x = aw[base + ((4*lh+0)<<6) + bb];
                    v.y = aw[base + ((4*lh+1)<<6) + bb];
                    v.z = aw[base + ((4*lh+2)<<6) + bb];
                    v.w = aw[base + ((4*lh+3)<<6) + bb];
                }
                attB[q] = v;
            }
        }
        #pragma unroll
        for (int kt = 0; kt < 2; ++kt) {
            f32x4 uc[4][2];                         // [blade q][mt&1]
            #pragma unroll
            for (int mte = 0; mte < 2; ++mte) {
                const int mt = 2*kt + mte;
                #pragma unroll
                for (int q = 0; q < 4; ++q) {
                    U4B a;  a.u  = wsu[((mt<<3) + jh*4 + q)*64 + b];
                    U4B bb; bb.u = attB[q];
                    f32x4 z; z[0]=0.f; z[1]=0.f; z[2]=0.f; z[3]=0.f;
                    uc[q][mte] = __builtin_amdgcn_mfma_f32_16x16x32_bf16(a.h, bb.h, z, 0, 0, 0);
                }
                // silu in C'-layout: lane holds (b=lcol-col, m2 = m2base + r)
                const int m2base = 32*kt + 4*mte + 8*lh;
                const float4 bup4 = *(const float4*)&b_up[m2base];
                const float* bupp = &bup4.x;
                #pragma unroll
                for (int r = 0; r < 4; ++r) {
                    const float4 aa = *(const float4*)&a_act[(m2base + r)*4];
                    const float4 bc = *(const float4*)&b_act[(m2base + r)*4];
                    float h0 = uc[0][mte][r], h1 = uc[1][mte][r];
                    float h2 = uc[2][mte][r], h3 = uc[3][mte][r];
                    if (jh == 0) {                   // blades 0..3: grade0 + grade1
                        h0 += bupp[r];
                        const float g0 = sigmoidf_(fmaf(aa.x, h0, bc.x));
                        const float g1 = sigmoidf_(fmaf(aa.y, h1*h1 + h2*h2 + h3*h3, bc.y));
                        h0 *= g0; h1 *= g1; h2 *= g1; h3 *= g1;
                    } else {                         // blades 4..7: grade2 + grade3
                        const float g2 = sigmoidf_(fmaf(aa.z, h0*h0 + h1*h1 + h2*h2, bc.z));
                        const float g3 = sigmoidf_(fmaf(aa.w, h3*h3, bc.w));
                        h0 *= g2; h1 *= g2; h2 *= g2; h3 *= g3;
                    }
                    uc[0][mte][r]=h0; uc[1][mte][r]=h1; uc[2][mte][r]=h2; uc[3][mte][r]=h3;
                }
            }
            // pack down-A from same-lane regs and accumulate (K=32 full)
            #pragma unroll
            for (int q = 0; q < 4; ++q) {
                U4B a;
                a.u.x = pk2(uc[q][0][0], uc[q][0][1]);
                a.u.y = pk2(uc[q][0][2], uc[q][0][3]);
                a.u.z = pk2(uc[q][1][0], uc[q][1][1]);
                a.u.w = pk2(uc[q][1][2], uc[q][1][3]);
                U4B wb; wb.u = wsd[((kt<<3) + jh*4 + q)*64 + b];
                dC[q] = __builtin_amdgcn_mfma_f32_16x16x32_bf16(a.h, wb.h, dC[q], 0, 0, 0);
            }
        }
    }
    __syncthreads();         // all waves done reading gp/attW; X region reusable
    // --- down result -> X f32 in [b][m*8+i] layout (dC: col=m=lcol, row=b-local=4*lh+r) ---
    #pragma unroll
    for (int r = 0; r < 4; ++r) {
        const int br = Mtb + (lh<<2) + r;
        *(float4*)&sm[OFF_X + br*XS + (lcol<<3) + (jh<<2)] =
            make_float4(dC[0][r], dC[1][r], dC[2][r], dC[3][r]);
    }
    __syncthreads();

    // ---------- epilogue: out = attended + down + b_down ----------
    {
        const float bdA = b_down[mA], bdB = b_down[mB];
        float4 a0 = *(const float4*)&sm[OFF_X + b*XS + mA*8];
        float4 a1 = *(const float4*)&sm[OFF_X + b*XS + mA*8 + 4];
        float4 b0 = *(const float4*)&sm[OFF_X + b*XS + mB*8];
        float4 b1 = *(const float4*)&sm[OFF_X + b*XS + mB*8 + 4];
        *(float4*)&sm[OFF_X + b*XS + mA*8]     = make_float4(attA[0]+a0.x+bdA, attA[1]+a0.y,
                                                             attA[2]+a0.z,     attA[3]+a0.w);
        *(float4*)&sm[OFF_X + b*XS + mA*8 + 4] = make_float4(attA[4]+a1.x, attA[5]+a1.y,
                                                             attA[6]+a1.z, attA[7]+a1.w);
        *(float4*)&sm[OFF_X + b*XS + mB*8]     = make_float4(attB_[0]+b0.x+bdB, attB_[1]+b0.y,
                                                             attB_[2]+b0.z,     attB_[3]+b0.w);
        *(float4*)&sm[OFF_X + b*XS + mB*8 + 4] = make_float4(attB_[4]+b1.x, attB_[5]+b1.y,
                                                             attB_[6]+b1.z, attB_[7]+b1.w);
    }
    __syncthreads();
    {
        float4* og = (float4*)outg + (size_t)g * 2048;
        #pragma unroll
        for (int r = 0; r < 4; ++r) {
            const int idx = r * TPB + t;
            const int el = idx >> 5, off = idx & 31;
            og[idx] = *(const float4*)&sm[OFF_X + el * XS + off * 4];
        }
    }
}

extern "C" void kernel_launch(void* const* d_in, const int* in_sizes, int n_in,
                              void* d_out, int out_size, void* d_ws, size_t ws_size,
                              hipStream_t stream) {
    const float* x       = (const float*)d_in[0];
    const float* w_right = (const float*)d_in[1];
    const float* a_norm  = (const float*)d_in[2];
    const float* w_gp    = (const float*)d_in[3];
    const float* w_left  = (const float*)d_in[4];
    const float* b_left  = (const float*)d_in[5];
    const float* w_up    = (const float*)d_in[6];
    const float* b_up    = (const float*)d_in[7];
    const float* a_act   = (const float*)d_in[8];
    const float* b_act   = (const float*)d_in[9];
    const float* w_down  = (const float*)d_in[10];
    const float* b_down  = (const float*)d_in[11];
    float* out = (float*)d_out;

    const int B = in_sizes[0] / 128;        // 65536
    const int nblocks = B / 64;             // 1024

    unsigned* wsu = (unsigned*)d_ws;        // 32 KB up A-frags (pi-ordered)
    unsigned* wsd = wsu + 8192;             // 16 KB down B-frags (K=32)
    uint4*    wsg = (uint4*)(wsd + 4096);   // 22.5 KB gp B-frags (22 slot-pairs x 64 lanes)

    prep_pack<<<54, 256, 0, stream>>>(w_up, w_down, w_gp, wsu, wsd, wsg);

    (void)hipFuncSetAttribute((const void*)mv_block_kernel,
                              hipFuncAttributeMaxDynamicSharedMemorySize, SMEM_BYTES);
    mv_block_kernel<<<nblocks, TPB, SMEM_BYTES, stream>>>(
        x, w_right, a_norm, w_gp, w_left, b_left,
        w_up, b_up, a_act, b_act, w_down, b_down,
        (const uint4*)wsu, (const uint4*)wsd, (const uint4*)wsg, out);
}